// Round 22
// baseline (55.518 us; speedup 1.0000x reference)
//
#include <hip/hip_runtime.h>
#include <hip/hip_bf16.h>

// SCE loss: loss = mean_e [ logsumexp_j(parts[e].centers[j]) - parts[e].centers[e] ]
// K=16384, D=128, fp32 inputs, scalar fp32 output.
//
//  k1: fp32 -> fp8(e4m3) convert + fused fp32 diagonal dot. parts -> pb8
//      [K][128] row-major (scaled by log2 e); centers -> cbI8 permuted so
//      each 2KB jblock reads back as lane-CONTIGUOUS 16B chunks:
//      [jb][half][lg][row16][16B]  (R22: kills the 4-way bank conflict —
//      2.1M conflicts = 4 extra cyc per ds_read_b128 in R17-R21).
//  k2: sum-of-exp2 GEMM, mfma_scale_f32_16x16x128_f8f6f4 (unit scales).
//      R22: all 8 MFMAs issued into 8 NAMED accs, then all 8 esums.
//      CDNA issues in order: the old mfma;esum;mfma;... order stalled the
//      wave on each MFMA's ~100cyc result latency (serial chain = the
//      820-vs-600 cyc/tile gap). Now MFMAs stream back-to-back; esum0's
//      operand is long ready when it issues. 1024 blocks (1 generation/CU),
//      4-tile rounds, 1 barrier/round, LDS 32KB.
//  k3: finalize: 1 thread/row: sum 16 split partials + rowdot -> rowloss;
//      LDS-reduce -> 64 block partials (no atomics).
//  k4: reduce 64 partials -> mean.

#define K_DIM 16384
#define D_DIM 128
#define NSPLIT 16
#define COLS_PER_SPLIT (K_DIM / NSPLIT)          // 1024
#define TILES_PER_SPLIT (COLS_PER_SPLIT / 32)    // 32
#define RTILES 4
#define NROUND (TILES_PER_SPLIT / RTILES)        // 8

typedef __attribute__((ext_vector_type(8)))  int    i32x8;
typedef __attribute__((ext_vector_type(4)))  float  f32x4;
typedef __attribute__((ext_vector_type(2)))  float  f32x2;

__device__ __forceinline__ unsigned pack_fp8x4(float f0, float f1, float f2, float f3) {
    int r = 0;
    r = __builtin_amdgcn_cvt_pk_fp8_f32(f0, f1, r, false);  // bytes 0,1
    r = __builtin_amdgcn_cvt_pk_fp8_f32(f2, f3, r, true);   // bytes 2,3
    return (unsigned)r;
}

__global__ void convert_kernel(const float* __restrict__ parts,
                               const float* __restrict__ centers,
                               unsigned* __restrict__ pb8,    // [K][128] row-major
                               unsigned* __restrict__ cbI8,   // permuted jblocks
                               float* __restrict__ rowdot) {  // [K]
    const float LOG2E = 1.4426950408889634f;
    int i = blockIdx.x * blockDim.x + threadIdx.x;   // one thread per 4 elems
    const int lane = threadIdx.x & 63;

    f32x4 p = reinterpret_cast<const f32x4*>(parts)[i];
    f32x4 c = reinterpret_cast<const f32x4*>(centers)[i];
    pb8[i] = pack_fp8x4(p[0] * LOG2E, p[1] * LOG2E, p[2] * LOG2E, p[3] * LOG2E);

    const int e0v = i * 4;
    const int j   = e0v >> 7;        // row
    const int d0  = e0v & 127;       // col
    // cbI8 byte (j,d): jb=j>>4, j15=j&15, lg=d>>5, half=(d>>4)&1, rem=d&15
    // -> jb*2048 + half*1024 + lg*256 + j15*16 + rem
    const int byte_off = ((j >> 4) << 11) + (((d0 >> 4) & 1) << 10)
                       + ((d0 >> 5) << 8) + ((j & 15) << 4) + (d0 & 15);
    cbI8[byte_off >> 2] = pack_fp8x4(c[0], c[1], c[2], c[3]);

    // fused fp32 diagonal dot: 32 consecutive threads own one row
    float dd = p[0] * c[0] + p[1] * c[1] + p[2] * c[2] + p[3] * c[3];
#pragma unroll
    for (int off = 16; off > 0; off >>= 1)
        dd += __shfl_xor(dd, off);       // stays within each 32-lane half
    if ((lane & 31) == 0)
        rowdot[j] = dd;
}

// Partial sum-of-exp2 (base-2). One wave: 64 e-rows x one split.
// 16x16x128 MX-fp8 MFMA; A-tiles in LDS with lane*16-contiguous reads;
// per tile: 8 MFMAs into 8 named accs, THEN 8 esums (in-order issue fix).
__launch_bounds__(256, 4)
__global__ void lse_gemm_kernel(const unsigned char* __restrict__ P8,   // pb8 [K][128]
                                const unsigned char* __restrict__ CI8,  // cbI8
                                float* __restrict__ Sout) {             // [K][NSPLIT]
    // 2 pairs x 4 tiles x 4KB = 32KB
    __shared__ __attribute__((aligned(128))) unsigned char As[2][RTILES][4096];

    const int bid   = blockIdx.x;                 // 1024 blocks
    const int xcd    = bid & 7;                   // XCD-aware remap
    const int k      = bid >> 3;                  // 0..127
    const int split  = xcd * 2 + (k & 1);         // 0..15
    const int rowblk = k >> 1;                    // 0..63
    const int tid   = threadIdx.x;
    const int lane  = tid & 63;
    const int w     = tid >> 6;
    const int l15   = lane & 15;
    const int lg    = lane >> 4;                  // lane group 0..3
    const int rowgrp = rowblk * 4 + w;            // 0..255
    const int e0    = rowgrp * 64;
    const int lane16 = lane * 16;

    // B fragments (parts rows): eblock eb, lane -> col e0+eb*16+l15,
    // k-bytes lg*32..+31 of that row. 4 x i32x8 = 32 VGPR.
    i32x8 bf[4];
#pragma unroll
    for (int eb = 0; eb < 4; ++eb) {
        const unsigned char* pr = P8 + (size_t)(e0 + eb * 16 + l15) * D_DIM + lg * 32;
#pragma unroll
        for (int q = 0; q < 4; ++q) {
            bf[eb][q]     = reinterpret_cast<const int*>(pr)[q];
            bf[eb][q + 4] = reinterpret_cast<const int*>(pr + 16)[q];
        }
    }

    const int j0 = split * COLS_PER_SPLIT;
    // Staging: thread tid copies 16B, linear (tile is 4KB contiguous).
    const unsigned char* gsrc = CI8 + (size_t)(j0 >> 4) * 2048 + tid * 16;

    const f32x4 zc = {};
    float s0 = 0.f, s1 = 0.f, s2 = 0.f, s3 = 0.f;

    auto esum4 = [&](const f32x4& acc) -> float {
        f32x2 v = {__builtin_amdgcn_exp2f(acc[0]), __builtin_amdgcn_exp2f(acc[1])};
        f32x2 u = {__builtin_amdgcn_exp2f(acc[2]), __builtin_amdgcn_exp2f(acc[3])};
        v += u;
        return v[0] + v[1];
    };

    auto do_tile = [&](const unsigned char* base) {
        i32x8 aA, aB;                 // jblock 0 and 1 fragments (contiguous reads)
#pragma unroll
        for (int q = 0; q < 4; ++q) {
            aA[q]     = reinterpret_cast<const int*>(base + lane16)[q];
            aA[q + 4] = reinterpret_cast<const int*>(base + 1024 + lane16)[q];
            aB[q]     = reinterpret_cast<const int*>(base + 2048 + lane16)[q];
            aB[q + 4] = reinterpret_cast<const int*>(base + 3072 + lane16)[q];
        }
        // issue ALL MFMAs first (independent; no in-order stall) ...
        f32x4 c0 = __builtin_amdgcn_mfma_scale_f32_16x16x128_f8f6f4(aA, bf[0], zc, 0, 0, 0, 0x7F, 0, 0x7F);
        f32x4 c1 = __builtin_amdgcn_mfma_scale_f32_16x16x128_f8f6f4(aB, bf[0], zc, 0, 0, 0, 0x7F, 0, 0x7F);
        f32x4 c2 = __builtin_amdgcn_mfma_scale_f32_16x16x128_f8f6f4(aA, bf[1], zc, 0, 0, 0, 0x7F, 0, 0x7F);
        f32x4 c3 = __builtin_amdgcn_mfma_scale_f32_16x16x128_f8f6f4(aB, bf[1], zc, 0, 0, 0, 0x7F, 0, 0x7F);
        f32x4 c4 = __builtin_amdgcn_mfma_scale_f32_16x16x128_f8f6f4(aA, bf[2], zc, 0, 0, 0, 0x7F, 0, 0x7F);
        f32x4 c5 = __builtin_amdgcn_mfma_scale_f32_16x16x128_f8f6f4(aB, bf[2], zc, 0, 0, 0, 0x7F, 0, 0x7F);
        f32x4 c6 = __builtin_amdgcn_mfma_scale_f32_16x16x128_f8f6f4(aA, bf[3], zc, 0, 0, 0, 0x7F, 0, 0x7F);
        f32x4 c7 = __builtin_amdgcn_mfma_scale_f32_16x16x128_f8f6f4(aB, bf[3], zc, 0, 0, 0, 0x7F, 0, 0x7F);
        // ... then all esums (operands ready; wave doesn't stall)
        s0 += esum4(c0); s0 += esum4(c1);
        s1 += esum4(c2); s1 += esum4(c3);
        s2 += esum4(c4); s2 += esum4(c5);
        s3 += esum4(c6); s3 += esum4(c7);
    };

    // prologue: stage tiles 0..3 into pair 0 (16B/thread/tile, sequential)
#pragma unroll
    for (int i = 0; i < RTILES; ++i) {
        int4 rg = *reinterpret_cast<const int4*>(gsrc + (size_t)i * 4096);
        *reinterpret_cast<int4*>(&As[0][i][tid * 16]) = rg;
    }
    __syncthreads();

    for (int r = 0; r < NROUND; ++r) {
        const int cur = r & 1;
        const int nxt = cur ^ 1;
        const bool pf = (r + 1 < NROUND);

#pragma unroll
        for (int i = 0; i < RTILES; ++i) {
            int4 rg;
            if (pf) rg = *reinterpret_cast<const int4*>(
                gsrc + (size_t)(RTILES * (r + 1) + i) * 4096);
            do_tile(&As[cur][i][0]);
            if (pf) *reinterpret_cast<int4*>(&As[nxt][i][tid * 16]) = rg;
        }
        __syncthreads();
    }

    // lane groups cover disjoint j-sets for the same e-col -> combine.
    s0 += __shfl_xor(s0, 16); s0 += __shfl_xor(s0, 32);
    s1 += __shfl_xor(s1, 16); s1 += __shfl_xor(s1, 32);
    s2 += __shfl_xor(s2, 16); s2 += __shfl_xor(s2, 32);
    s3 += __shfl_xor(s3, 16); s3 += __shfl_xor(s3, 32);

    if (lane < 16) {
        Sout[(size_t)(e0 + lane) * NSPLIT + split]      = s0;
        Sout[(size_t)(e0 + 16 + lane) * NSPLIT + split] = s1;
        Sout[(size_t)(e0 + 32 + lane) * NSPLIT + split] = s2;
        Sout[(size_t)(e0 + 48 + lane) * NSPLIT + split] = s3;
    }
}

// One thread per row: combine split partials -> rowloss; LDS-reduce -> partial.
__global__ void finalize_kernel(const float* __restrict__ Sp,      // [K][NSPLIT]
                                const float* __restrict__ rowdot,  // [K]
                                float* __restrict__ partial) {     // [64]
    __shared__ float sm[256];
    const int row = blockIdx.x * 256 + threadIdx.x;

    const f32x4* sp = reinterpret_cast<const f32x4*>(Sp + (size_t)row * NSPLIT);
    float S = 0.0f;
#pragma unroll
    for (int q = 0; q < NSPLIT / 4; ++q) {
        f32x4 v = sp[q];
        S += (v[0] + v[1]) + (v[2] + v[3]);
    }
    const float LN2 = 0.6931471805599453f;
    float loss = LN2 * __builtin_amdgcn_logf(S) - rowdot[row];  // v_log_f32 = log2

    sm[threadIdx.x] = loss;
    __syncthreads();
    for (int off = 128; off > 0; off >>= 1) {
        if (threadIdx.x < off) sm[threadIdx.x] += sm[threadIdx.x + off];
        __syncthreads();
    }
    if (threadIdx.x == 0)
        partial[blockIdx.x] = sm[0];
}

__global__ void reduce_kernel(const float* __restrict__ partial, float* __restrict__ out) {
    const int lane = threadIdx.x;   // 64 threads
    float v = partial[lane];
#pragma unroll
    for (int off = 32; off > 0; off >>= 1)
        v += __shfl_xor(v, off);
    if (lane == 0)
        out[0] = v / (float)K_DIM;
}

extern "C" void kernel_launch(void* const* d_in, const int* in_sizes, int n_in,
                              void* d_out, int out_size, void* d_ws, size_t ws_size,
                              hipStream_t stream) {
    const float* parts   = (const float*)d_in[0];
    const float* centers = (const float*)d_in[1];
    float* out = (float*)d_out;

    char* ws = (char*)d_ws;
    unsigned* pb8  = (unsigned*)ws;                            // 2 MB
    unsigned* cbI8 = (unsigned*)(ws + 2u * 1024 * 1024);       // 2 MB
    float*  Sp  = (float*)(ws + 4u * 1024 * 1024);             // 1 MB (K*16 f32)
    float*  rowdot  = Sp + (size_t)K_DIM * NSPLIT;             // 64 KB
    float*  partial = rowdot + K_DIM;                          // 256 B

    const int n4 = (K_DIM * D_DIM) / 4;
    convert_kernel<<<n4 / 256, 256, 0, stream>>>(parts, centers, pb8, cbI8, rowdot);
    lse_gemm_kernel<<<(K_DIM / 256) * NSPLIT, 256, 0, stream>>>(
        (const unsigned char*)pb8, (const unsigned char*)cbI8, Sp);
    finalize_kernel<<<K_DIM / 256, 256, 0, stream>>>(Sp, rowdot, partial);
    reduce_kernel<<<1, 64, 0, stream>>>(partial, out);
}

// Round 23
// 52.602 us; speedup vs baseline: 1.0554x; 1.0554x over previous
//
#include <hip/hip_runtime.h>
#include <hip/hip_bf16.h>

// SCE loss: loss = mean_e [ logsumexp_j(parts[e].centers[j]) - parts[e].centers[e] ]
// K=16384, D=128, fp32 inputs, scalar fp32 output.
//
//  k1: fp32 -> fp8(e4m3) convert + fused fp32 diagonal dot. parts -> pb8
//      [K][128] row-major (scaled by log2 e); centers -> cbI8 permuted so
//      each 2KB jblock reads back lane-CONTIGUOUS ([half][lg][row16][16B]).
//  k2: sum-of-exp2 GEMM, mfma_scale_f32_16x16x128_f8f6f4 (unit scales).
//      R23 = R21's exact loop structure (serial acc=mfma; s+=esum per step —
//      the compiler pipelines it; R22's manual 8-acc batching REGRESSED,
//      confirming don't-hand-schedule) + R22's conflict-free LDS layout
//      (isolated: conflicts 2.1M->0 with no acc restructure).
//      1024 blocks = 1 generation/CU; 4-tile rounds; 1 barrier/round.
//  k3: finalize: 1 thread/row: sum 16 split partials + rowdot -> rowloss;
//      LDS-reduce -> 64 block partials (no atomics).
//  k4: reduce 64 partials -> mean.

#define K_DIM 16384
#define D_DIM 128
#define NSPLIT 16
#define COLS_PER_SPLIT (K_DIM / NSPLIT)          // 1024
#define TILES_PER_SPLIT (COLS_PER_SPLIT / 32)    // 32
#define RTILES 4
#define NROUND (TILES_PER_SPLIT / RTILES)        // 8

typedef __attribute__((ext_vector_type(8)))  int    i32x8;
typedef __attribute__((ext_vector_type(4)))  float  f32x4;
typedef __attribute__((ext_vector_type(2)))  float  f32x2;

__device__ __forceinline__ unsigned pack_fp8x4(float f0, float f1, float f2, float f3) {
    int r = 0;
    r = __builtin_amdgcn_cvt_pk_fp8_f32(f0, f1, r, false);  // bytes 0,1
    r = __builtin_amdgcn_cvt_pk_fp8_f32(f2, f3, r, true);   // bytes 2,3
    return (unsigned)r;
}

__global__ void convert_kernel(const float* __restrict__ parts,
                               const float* __restrict__ centers,
                               unsigned* __restrict__ pb8,    // [K][128] row-major
                               unsigned* __restrict__ cbI8,   // permuted jblocks
                               float* __restrict__ rowdot) {  // [K]
    const float LOG2E = 1.4426950408889634f;
    int i = blockIdx.x * blockDim.x + threadIdx.x;   // one thread per 4 elems
    const int lane = threadIdx.x & 63;

    f32x4 p = reinterpret_cast<const f32x4*>(parts)[i];
    f32x4 c = reinterpret_cast<const f32x4*>(centers)[i];
    pb8[i] = pack_fp8x4(p[0] * LOG2E, p[1] * LOG2E, p[2] * LOG2E, p[3] * LOG2E);

    const int e0v = i * 4;
    const int j   = e0v >> 7;        // row
    const int d0  = e0v & 127;       // col
    // cbI8 byte (j,d): jb=j>>4, j15=j&15, lg=d>>5, half=(d>>4)&1, rem=d&15
    // -> jb*2048 + half*1024 + lg*256 + j15*16 + rem
    const int byte_off = ((j >> 4) << 11) + (((d0 >> 4) & 1) << 10)
                       + ((d0 >> 5) << 8) + ((j & 15) << 4) + (d0 & 15);
    cbI8[byte_off >> 2] = pack_fp8x4(c[0], c[1], c[2], c[3]);

    // fused fp32 diagonal dot: 32 consecutive threads own one row
    float dd = p[0] * c[0] + p[1] * c[1] + p[2] * c[2] + p[3] * c[3];
#pragma unroll
    for (int off = 16; off > 0; off >>= 1)
        dd += __shfl_xor(dd, off);       // stays within each 32-lane half
    if ((lane & 31) == 0)
        rowdot[j] = dd;
}

// Partial sum-of-exp2 (base-2). One wave: 64 e-rows x one split.
// 16x16x128 MX-fp8 MFMA; A-tiles in LDS with lane*16-contiguous reads;
// R21's serial per-tile body (compiler-scheduled).
__launch_bounds__(256, 4)
__global__ void lse_gemm_kernel(const unsigned char* __restrict__ P8,   // pb8 [K][128]
                                const unsigned char* __restrict__ CI8,  // cbI8
                                float* __restrict__ Sout) {             // [K][NSPLIT]
    // 2 pairs x 4 tiles x 4KB = 32KB
    __shared__ __attribute__((aligned(128))) unsigned char As[2][RTILES][4096];

    const int bid   = blockIdx.x;                 // 1024 blocks
    const int xcd    = bid & 7;                   // XCD-aware remap
    const int k      = bid >> 3;                  // 0..127
    const int split  = xcd * 2 + (k & 1);         // 0..15
    const int rowblk = k >> 1;                    // 0..63
    const int tid   = threadIdx.x;
    const int lane  = tid & 63;
    const int w     = tid >> 6;
    const int l15   = lane & 15;
    const int lg    = lane >> 4;                  // lane group 0..3
    const int rowgrp = rowblk * 4 + w;            // 0..255
    const int e0    = rowgrp * 64;
    const int lane16 = lane * 16;

    // B fragments (parts rows): eblock eb, lane -> col e0+eb*16+l15,
    // k-bytes lg*32..+31 of that row. 4 x i32x8 = 32 VGPR.
    i32x8 bf[4];
#pragma unroll
    for (int eb = 0; eb < 4; ++eb) {
        const unsigned char* pr = P8 + (size_t)(e0 + eb * 16 + l15) * D_DIM + lg * 32;
#pragma unroll
        for (int q = 0; q < 4; ++q) {
            bf[eb][q]     = reinterpret_cast<const int*>(pr)[q];
            bf[eb][q + 4] = reinterpret_cast<const int*>(pr + 16)[q];
        }
    }

    const int j0 = split * COLS_PER_SPLIT;
    // Staging: thread tid copies 16B, linear (tile is 4KB contiguous).
    const unsigned char* gsrc = CI8 + (size_t)(j0 >> 4) * 2048 + tid * 16;

    const f32x4 zc = {};
    float s0 = 0.f, s1 = 0.f, s2 = 0.f, s3 = 0.f;

    auto esum4 = [&](const f32x4& acc) -> float {
        f32x2 v = {__builtin_amdgcn_exp2f(acc[0]), __builtin_amdgcn_exp2f(acc[1])};
        f32x2 u = {__builtin_amdgcn_exp2f(acc[2]), __builtin_amdgcn_exp2f(acc[3])};
        v += u;
        return v[0] + v[1];
    };

    auto do_tile = [&](const unsigned char* base) {
        i32x8 aA, aB;                 // jblock 0 and 1 fragments (contiguous reads)
#pragma unroll
        for (int q = 0; q < 4; ++q) {
            aA[q]     = reinterpret_cast<const int*>(base + lane16)[q];
            aA[q + 4] = reinterpret_cast<const int*>(base + 1024 + lane16)[q];
            aB[q]     = reinterpret_cast<const int*>(base + 2048 + lane16)[q];
            aB[q + 4] = reinterpret_cast<const int*>(base + 3072 + lane16)[q];
        }
        f32x4 acc;
        acc = __builtin_amdgcn_mfma_scale_f32_16x16x128_f8f6f4(aA, bf[0], zc, 0, 0, 0, 0x7F, 0, 0x7F);
        s0 += esum4(acc);
        acc = __builtin_amdgcn_mfma_scale_f32_16x16x128_f8f6f4(aB, bf[0], zc, 0, 0, 0, 0x7F, 0, 0x7F);
        s0 += esum4(acc);
        acc = __builtin_amdgcn_mfma_scale_f32_16x16x128_f8f6f4(aA, bf[1], zc, 0, 0, 0, 0x7F, 0, 0x7F);
        s1 += esum4(acc);
        acc = __builtin_amdgcn_mfma_scale_f32_16x16x128_f8f6f4(aB, bf[1], zc, 0, 0, 0, 0x7F, 0, 0x7F);
        s1 += esum4(acc);
        acc = __builtin_amdgcn_mfma_scale_f32_16x16x128_f8f6f4(aA, bf[2], zc, 0, 0, 0, 0x7F, 0, 0x7F);
        s2 += esum4(acc);
        acc = __builtin_amdgcn_mfma_scale_f32_16x16x128_f8f6f4(aB, bf[2], zc, 0, 0, 0, 0x7F, 0, 0x7F);
        s2 += esum4(acc);
        acc = __builtin_amdgcn_mfma_scale_f32_16x16x128_f8f6f4(aA, bf[3], zc, 0, 0, 0, 0x7F, 0, 0x7F);
        s3 += esum4(acc);
        acc = __builtin_amdgcn_mfma_scale_f32_16x16x128_f8f6f4(aB, bf[3], zc, 0, 0, 0, 0x7F, 0, 0x7F);
        s3 += esum4(acc);
    };

    // prologue: stage tiles 0..3 into pair 0 (16B/thread/tile, sequential)
#pragma unroll
    for (int i = 0; i < RTILES; ++i) {
        int4 rg = *reinterpret_cast<const int4*>(gsrc + (size_t)i * 4096);
        *reinterpret_cast<int4*>(&As[0][i][tid * 16]) = rg;
    }
    __syncthreads();

    for (int r = 0; r < NROUND; ++r) {
        const int cur = r & 1;
        const int nxt = cur ^ 1;
        const bool pf = (r + 1 < NROUND);

#pragma unroll
        for (int i = 0; i < RTILES; ++i) {
            int4 rg;
            if (pf) rg = *reinterpret_cast<const int4*>(
                gsrc + (size_t)(RTILES * (r + 1) + i) * 4096);
            do_tile(&As[cur][i][0]);
            if (pf) *reinterpret_cast<int4*>(&As[nxt][i][tid * 16]) = rg;
        }
        __syncthreads();
    }

    // lane groups cover disjoint j-sets for the same e-col -> combine.
    s0 += __shfl_xor(s0, 16); s0 += __shfl_xor(s0, 32);
    s1 += __shfl_xor(s1, 16); s1 += __shfl_xor(s1, 32);
    s2 += __shfl_xor(s2, 16); s2 += __shfl_xor(s2, 32);
    s3 += __shfl_xor(s3, 16); s3 += __shfl_xor(s3, 32);

    if (lane < 16) {
        Sout[(size_t)(e0 + lane) * NSPLIT + split]      = s0;
        Sout[(size_t)(e0 + 16 + lane) * NSPLIT + split] = s1;
        Sout[(size_t)(e0 + 32 + lane) * NSPLIT + split] = s2;
        Sout[(size_t)(e0 + 48 + lane) * NSPLIT + split] = s3;
    }
}

// One thread per row: combine split partials -> rowloss; LDS-reduce -> partial.
__global__ void finalize_kernel(const float* __restrict__ Sp,      // [K][NSPLIT]
                                const float* __restrict__ rowdot,  // [K]
                                float* __restrict__ partial) {     // [64]
    __shared__ float sm[256];
    const int row = blockIdx.x * 256 + threadIdx.x;

    const f32x4* sp = reinterpret_cast<const f32x4*>(Sp + (size_t)row * NSPLIT);
    float S = 0.0f;
#pragma unroll
    for (int q = 0; q < NSPLIT / 4; ++q) {
        f32x4 v = sp[q];
        S += (v[0] + v[1]) + (v[2] + v[3]);
    }
    const float LN2 = 0.6931471805599453f;
    float loss = LN2 * __builtin_amdgcn_logf(S) - rowdot[row];  // v_log_f32 = log2

    sm[threadIdx.x] = loss;
    __syncthreads();
    for (int off = 128; off > 0; off >>= 1) {
        if (threadIdx.x < off) sm[threadIdx.x] += sm[threadIdx.x + off];
        __syncthreads();
    }
    if (threadIdx.x == 0)
        partial[blockIdx.x] = sm[0];
}

__global__ void reduce_kernel(const float* __restrict__ partial, float* __restrict__ out) {
    const int lane = threadIdx.x;   // 64 threads
    float v = partial[lane];
#pragma unroll
    for (int off = 32; off > 0; off >>= 1)
        v += __shfl_xor(v, off);
    if (lane == 0)
        out[0] = v / (float)K_DIM;
}

extern "C" void kernel_launch(void* const* d_in, const int* in_sizes, int n_in,
                              void* d_out, int out_size, void* d_ws, size_t ws_size,
                              hipStream_t stream) {
    const float* parts   = (const float*)d_in[0];
    const float* centers = (const float*)d_in[1];
    float* out = (float*)d_out;

    char* ws = (char*)d_ws;
    unsigned* pb8  = (unsigned*)ws;                            // 2 MB
    unsigned* cbI8 = (unsigned*)(ws + 2u * 1024 * 1024);       // 2 MB
    float*  Sp  = (float*)(ws + 4u * 1024 * 1024);             // 1 MB (K*16 f32)
    float*  rowdot  = Sp + (size_t)K_DIM * NSPLIT;             // 64 KB
    float*  partial = rowdot + K_DIM;                          // 256 B

    const int n4 = (K_DIM * D_DIM) / 4;
    convert_kernel<<<n4 / 256, 256, 0, stream>>>(parts, centers, pb8, cbI8, rowdot);
    lse_gemm_kernel<<<(K_DIM / 256) * NSPLIT, 256, 0, stream>>>(
        (const unsigned char*)pb8, (const unsigned char*)cbI8, Sp);
    finalize_kernel<<<K_DIM / 256, 256, 0, stream>>>(Sp, rowdot, partial);
    reduce_kernel<<<1, 64, 0, stream>>>(partial, out);
}